// Round 8
// baseline (1810.617 us; speedup 1.0000x reference)
//
#include <hip/hip_runtime.h>
#include <stdint.h>

// ---------------------------------------------------------------------------
// FixedPointLSTM (B=64, T=256, I=512, H=1024), fixed-point Q8.8 with hard
// activations. All fxp grid values are exactly representable in fp16; fp16
// MFMA with fp32 accumulate matches the numpy reference to ~1 grid step.
//
// R8 == R7 with the LDS staging index fixed. R7's failure was a factor-of-8
// bug: sb used ((tid>>5)<<3)*264 instead of (tid>>5)*264, scattering staging
// writes out of bounds (kt up to 80 of 32). Protocol unchanged:
// single-hop tagged handoff (h word = (step_tag<<16)|h_fp16, relaxed agent
// atomics, no drain/flag/release on the critical path), flow control via
// per-rank staged-counters polled concurrently with MFMA, LDS [kt=32][264]
// tiling for conflict-free fragment reads and <=2-way staging writes.
// ---------------------------------------------------------------------------

typedef _Float16 h8 __attribute__((ext_vector_type(8)));
typedef _Float16 h4 __attribute__((ext_vector_type(4)));
typedef float f4 __attribute__((ext_vector_type(4)));

#define MFMA16(a, b, c) __builtin_amdgcn_mfma_f32_16x16x32_f16(a, b, c, 0, 0, 0)

__device__ __forceinline__ float fxp(float x) {
  float q = rintf(x * 256.0f) * 0.00390625f;
  return fminf(fmaxf(q, -128.0f), 127.99609375f);
}

// round-only variant: for values provably inside [-128, 127.996] (activation
// outputs in [-1,1] / [0,1]) the clamp is a no-op and dropped.
__device__ __forceinline__ float fxp_rnd(float x) {
  return rintf(x * 256.0f) * 0.00390625f;
}

__device__ __forceinline__ float hsig(float x) {
  return fminf(fmaxf(x / 6.0f + 0.5f, 0.0f), 1.0f);  // IEEE div to match np
}

// ---- quantize fp32 -> fxp grid, store fp16 ---------------------------------
__global__ void qf16_kernel(const float* __restrict__ in,
                            _Float16* __restrict__ out, int n4) {
  int i = blockIdx.x * 256 + threadIdx.x;
  if (i < n4) {
    float4 v = ((const float4*)in)[i];
    h4 o;
    o[0] = (_Float16)fxp(v.x); o[1] = (_Float16)fxp(v.y);
    o[2] = (_Float16)fxp(v.z); o[3] = (_Float16)fxp(v.w);
    ((h4*)out)[i] = o;
  }
}

// quantize + transpose x: in [64][256][512] -> rows m = t*64+b, [16384][512]
__global__ void qx_kernel(const float* __restrict__ in,
                          _Float16* __restrict__ out) {
  int i4 = blockIdx.x * 256 + threadIdx.x;  // over 16384*128 float4s
  int col4 = i4 & 127;
  int row = i4 >> 7;  // b*256 + t
  int b = row >> 8, tt = row & 255;
  float4 v = ((const float4*)in)[i4];
  h4 o;
  o[0] = (_Float16)fxp(v.x); o[1] = (_Float16)fxp(v.y);
  o[2] = (_Float16)fxp(v.z); o[3] = (_Float16)fxp(v.w);
  ((h4*)out)[(size_t)((tt << 6) + b) * 128 + col4] = o;
}

__global__ void qf32_kernel(const float* __restrict__ in,
                            float* __restrict__ out, int n4) {
  int i = blockIdx.x * 256 + threadIdx.x;
  if (i < n4) {
    float4 v = ((const float4*)in)[i];
    float4 o;
    o.x = fxp(v.x); o.y = fxp(v.y); o.z = fxp(v.z); o.w = fxp(v.w);
    ((float4*)out)[i] = o;
  }
}

// h0 -> htag buffer 0 (tag = 0): [grp=8][buf=2][row=8][1024] u32
__global__ void qh0_kernel(const float* __restrict__ in,
                           uint32_t* __restrict__ htag) {
  int i4 = blockIdx.x * 256 + threadIdx.x;  // over 16384 float4s
  int b = i4 >> 8;                          // 256 float4 per batch row
  int col = (i4 & 255) << 2;
  int grp = b >> 3, row = b & 7;
  float4 v = ((const float4*)in)[i4];
  uint4 o;
  o.x = (uint32_t)__builtin_bit_cast(unsigned short, (_Float16)fxp(v.x));
  o.y = (uint32_t)__builtin_bit_cast(unsigned short, (_Float16)fxp(v.y));
  o.z = (uint32_t)__builtin_bit_cast(unsigned short, (_Float16)fxp(v.z));
  o.w = (uint32_t)__builtin_bit_cast(unsigned short, (_Float16)fxp(v.w));
  *(uint4*)(htag + (size_t)grp * 16384 + row * 1024 + col) = o;
}

// ---- async global->LDS helper (width 16B; LDS dest = wave-uniform base) ----
__device__ __forceinline__ void gload_lds16(const _Float16* g, _Float16* l) {
  __builtin_amdgcn_global_load_lds(
      (const __attribute__((address_space(1))) uint32_t*)g,
      (__attribute__((address_space(3))) uint32_t*)l, 16, 0, 0);
}

// ---------------------------------------------------------------------------
// gx = fxp(x_q @ w_ih_q^T + b_ih_q), packed [T=256][oct=8][rank=32][slot=128][8]
// fp16 (128 MB). slot = (w<<5)|(qh<<4)|(gate&1)<<3|(j&7); per-entry 8 fp16 =
// [tile0 r=0..3 | tile1 r=0..3], tile = gate>>1, r = b&3, qh = (b>>2)&1.
// ---------------------------------------------------------------------------
__global__ __launch_bounds__(256) void gemm_gx_kernel(
    const _Float16* __restrict__ Xq,   // [16384][512], m = t*64+b
    const _Float16* __restrict__ Wih,  // [4096][512]
    const float* __restrict__ bih,     // [4096]
    _Float16* __restrict__ gx)         // packed, see above
{
  __shared__ _Float16 As[128 * 32];
  __shared__ _Float16 Bs[128 * 32];
  const int tid = threadIdx.x;
  const int lane = tid & 63;
  const int w = tid >> 6;
  const int wm = (w >> 1) * 64;
  const int wn = (w & 1) * 64;
  const int m0 = blockIdx.x * 128;
  const int n0 = blockIdx.y * 128;
  const int cl = lane & 15, q = lane >> 4;

  f4 acc[4][4] = {};

  for (int k0 = 0; k0 < 512; k0 += 32) {
#pragma unroll
    for (int i = 0; i < 2; i++) {
      int idx = i * 256 + tid;
      int row = idx >> 2;
      int kc = (idx & 3) << 3;
      int wbase = (i * 256 + (tid & 192)) << 3;  // wave-uniform LDS base
      gload_lds16(Xq + (size_t)(m0 + row) * 512 + k0 + kc, As + wbase);
      gload_lds16(Wih + (size_t)(n0 + row) * 512 + k0 + kc, Bs + wbase);
    }
    __syncthreads();
    h8 af[4], bf[4];
#pragma unroll
    for (int mt = 0; mt < 4; mt++)
      af[mt] = *(const h8*)(As + (wm + mt * 16 + cl) * 32 + q * 8);
#pragma unroll
    for (int nt = 0; nt < 4; nt++)
      bf[nt] = *(const h8*)(Bs + (wn + nt * 16 + cl) * 32 + q * 8);
#pragma unroll
    for (int mt = 0; mt < 4; mt++)
#pragma unroll
      for (int nt = 0; nt < 4; nt++)
        acc[mt][nt] = MFMA16(af[mt], bf[nt], acc[mt][nt]);
    __syncthreads();
  }

  const int g = n0 >> 10;  // whole n-block lies in one gate
  const int tile = g >> 1, g1 = g & 1;
#pragma unroll
  for (int nt = 0; nt < 4; nt++) {
    const int n = n0 + wn + nt * 16 + cl;
    const float bv = bih[n];
    const int j = n & 1023;
    const int rank = j >> 5, wq = (j >> 3) & 3, c7 = j & 7;
#pragma unroll
    for (int mt = 0; mt < 4; mt++) {
      const int m = m0 + wm + mt * 16 + q * 4;  // 4-aligned
      const int b = m & 63, tt = m >> 6;
      const int oct = b >> 3, qh = (b >> 2) & 1;
      const int slot = (wq << 5) | (qh << 4) | (g1 << 3) | c7;
      h4 pk;
#pragma unroll
      for (int r = 0; r < 4; r++) pk[r] = (_Float16)fxp(acc[mt][nt][r] + bv);
      *(h4*)(gx + ((((size_t)tt * 8 + oct) * 32 + rank) * 128 + slot) * 8 +
             tile * 4) = pk;
    }
  }
}

// ---------------------------------------------------------------------------
// Persistent recurrence. 256 blocks x 256 threads, a255 pin -> 1 block/CU ->
// all blocks co-resident. Block = (grp = blockIdx&7, rank = blockIdx>>3);
// group owns batch rows 8g..8g+7; rank owns h-cols rank*32..+31 x 4 gates
// (128 W_hh rows in regs). Per step:
//   stage: 32 coalesced tagged-word loads/thread, per-word tag retry
//   -> LDS [kt][264] tiles -> barrier (+tid0 sflag=t+1; w0 flow-poll) ->
//   MFMA -> gates (regs) -> barrier -> tagged h stores (t+1) + out stores.
// ---------------------------------------------------------------------------
__global__ __launch_bounds__(256, 1) void lstm_kernel(
    const _Float16* __restrict__ Whh,  // [4096][1024] quantized
    const float* __restrict__ bhh,     // [4096] quantized
    const _Float16* __restrict__ gx,   // packed [256][8][32][128][8]
    const float* __restrict__ c0,      // [64][1024]
    uint32_t* __restrict__ htag,       // [8][2][8][1024] tagged h words
    float* __restrict__ out,           // [64][256][1024] ++ h_n ++ c_n
    unsigned* __restrict__ sflag)      // [8][32] staged-step counters
{
  // Residency pin: force total regs/wave > 256 -> 1 wave/SIMD -> 1 block/CU.
  asm volatile("v_accvgpr_write_b32 a255, 0" ::: "a255");

  const int tid = threadIdx.x;
  const int lane = tid & 63;
  const int w = tid >> 6;
  const int cl = lane & 15, q = lane >> 4;
  const int g01 = (lane >> 3) & 1;
  const int c7 = lane & 7;

  const int grp = blockIdx.x & 7;    // batch octet
  const int rank = blockIdx.x >> 3;  // 32-column slice owner

  const int jbase = (rank << 5) + (w << 3);         // block/wave col base
  const int row0 = (g01 << 10) + jbase + c7;        // gates i/f
  const int row1 = ((g01 + 2) << 10) + jbase + c7;  // gates g/o

  // persistent B fragments: 2 tiles x 32 k-steps x 4 regs = 256 regs
  h8 B0[32], B1[32];
#pragma unroll
  for (int kt = 0; kt < 32; kt++) {
    B0[kt] = *(const h8*)(Whh + (size_t)row0 * 1024 + (kt << 5) + (q << 3));
    B1[kt] = *(const h8*)(Whh + (size_t)row1 * 1024 + (kt << 5) + (q << 3));
  }
  const float bh0 = bhh[row0], bh1 = bhh[row1];
  const int jc = jbase + c7;        // h column 0..1023
  const int lrow = ((q & 1) << 2);  // local batch row base (valid q<2)
  const bool writer = ((lane & 8) == 0) && (q < 2);

  float c_st[4], h_last[4];
#pragma unroll
  for (int r = 0; r < 4; r++) {
    c_st[r] = c0[((grp << 3) + lrow + r) * 1024 + jc];
    h_last[r] = 0.0f;
  }

  // LDS h stage: 32 k-tiles x (8 rows x 32 halves + 8 pad) = 264 halves/tile.
  // Staged word j*256+tid has global col (j&3)*256+tid -> tile kt =
  // (j&3)*8 + (tid>>5), row j>>2, colInTile tid&31:
  //   idx = kt*264 + row*32 + col = (tid>>5)*264 + (tid&31)   [sb]
  //         + (j&3)*2112 + (j>>2)*32.
  // (R7 bug: sb had (tid>>5)*2112 -> OOB scatter.)  Writes: 2-way banks.
  // Fragment read kt*264 + arow*32 + q*8 -> GEMM-like zero-conflict pattern.
  __shared__ alignas(16) _Float16 hs[32 * 264];
  unsigned short* hsu = (unsigned short*)hs;
  const int sb = (tid >> 5) * 264 + (tid & 31);
  const int arow = cl & 7;

  unsigned* myflag = sflag + (grp << 5) + rank;
  const unsigned* pollp = sflag + (grp << 5) + (lane & 31);

  for (int t = 0; t < 256; t++) {
    // prefetch gx_t: one coalesced 16B load per lane (overlaps staging)
    const h8 gv8 = *(const h8*)(
        gx +
        ((((size_t)t * 8 + grp) * 32 + rank) * 128 + ((w << 5) | (lane & 31))) *
            8);

    // ---- stage h_t with per-word tag validation (single IC hop) ----
    {
      const uint32_t* src = htag + ((size_t)grp * 2 + (t & 1)) * 8192;
      const uint32_t tg = (uint32_t)t;
      uint32_t vv[32];
#pragma unroll
      for (int j = 0; j < 32; j++)
        vv[j] = __hip_atomic_load(src + j * 256 + tid, __ATOMIC_RELAXED,
                                  __HIP_MEMORY_SCOPE_AGENT);
      int it = 0;
      for (;;) {
        uint32_t bad = 0;
#pragma unroll
        for (int j = 0; j < 32; j++) bad |= (vv[j] >> 16) ^ tg;
        if (bad == 0) break;
        if (++it > (1 << 18)) break;  // hang insurance (loudly wrong)
#pragma unroll
        for (int j = 0; j < 32; j++)
          if ((vv[j] >> 16) != tg)
            vv[j] = __hip_atomic_load(src + j * 256 + tid, __ATOMIC_RELAXED,
                                      __HIP_MEMORY_SCOPE_AGENT);
      }
#pragma unroll
      for (int j = 0; j < 32; j++)
        hsu[sb + (j & 3) * 2112 + (j >> 2) * 32] = (unsigned short)vv[j];
    }
    __syncthreads();

    if (tid == 0)
      __hip_atomic_store(myflag, (unsigned)(t + 1), __ATOMIC_RELAXED,
                         __HIP_MEMORY_SCOPE_AGENT);
    // flow control, off critical path: before overwriting buffer (t+1)&1
    // (holds step t-1), confirm all ranks staged step t-1 (counter >= t).
    // Satisfied a full step in advance -> usually zero iterations of wait.
    if (w == 0 && t) {
      const unsigned need = (unsigned)t;
      int it = 0;
      for (;;) {
        unsigned v = __hip_atomic_load(pollp, __ATOMIC_RELAXED,
                                       __HIP_MEMORY_SCOPE_AGENT);
        if (__ballot(v >= need) == ~0ull) break;
        if (++it > (1 << 17)) break;
        __builtin_amdgcn_s_sleep(1);
      }
    }

    f4 a0 = {}, a1 = {}, a2 = {}, a3 = {};
#pragma unroll
    for (int kt = 0; kt < 32; kt++) {
      h8 av = *(const h8*)(hs + kt * 264 + arow * 32 + (q << 3));
      if (kt & 1) { a1 = MFMA16(av, B0[kt], a1); a3 = MFMA16(av, B1[kt], a3); }
      else        { a0 = MFMA16(av, B0[kt], a0); a2 = MFMA16(av, B1[kt], a2); }
    }
    f4 g0 = a0 + a1;
    f4 g1 = a2 + a3;

#pragma unroll
    for (int r = 0; r < 4; r++) {
      float gv0 = fxp((float)gv8[r] + fxp(g0[r] + bh0));      // i or f
      float gv1 = fxp((float)gv8[4 + r] + fxp(g1[r] + bh1));  // g or o
      float s0 = fxp_rnd(hsig(gv0));                        // in [0,1]
      float s1t = fxp_rnd(fminf(fmaxf(gv1, -1.0f), 1.0f));  // in [-1,1]
      float s1s = fxp_rnd(hsig(gv1));
      float s1 = (lane & 8) ? s1s : s1t;
      float p0 = __shfl_xor(s0, 8);
      float p1 = __shfl_xor(s1, 8);
      float iv = writer ? s0 : p0;
      float fv = writer ? p0 : s0;
      float gv = writer ? s1 : p1;
      float ov = writer ? p1 : s1;
      float cn = fxp(fv * c_st[r] + iv * gv);
      c_st[r] = cn;
      h_last[r] = fxp_rnd(ov * fminf(fmaxf(cn, -1.0f), 1.0f));  // in [-1,1]
    }

    // barrier: (a) hs consumed by all waves before next step's staging
    // overwrites it, (b) w0's flow-control poll done before any h store.
    __syncthreads();

    if (writer) {
      uint32_t* dst = htag + ((size_t)grp * 2 + ((t + 1) & 1)) * 8192;
      const uint32_t tagw = (uint32_t)(t + 1) << 16;
#pragma unroll
      for (int r = 0; r < 4; r++) {
        uint32_t word =
            tagw |
            (uint32_t)__builtin_bit_cast(unsigned short, (_Float16)h_last[r]);
        __hip_atomic_store(dst + (lrow + r) * 1024 + jc, word, __ATOMIC_RELAXED,
                           __HIP_MEMORY_SCOPE_AGENT);
        __builtin_nontemporal_store(
            h_last[r],
            &out[((size_t)((grp << 3) + lrow + r) * 256 + t) * 1024 + jc]);
      }
    }
  }

  if (writer) {
#pragma unroll
    for (int r = 0; r < 4; r++) {
      out[16777216 + (size_t)((grp << 3) + lrow + r) * 1024 + jc] = h_last[r];
      out[16777216 + 65536 + (size_t)((grp << 3) + lrow + r) * 1024 + jc] =
          c_st[r];
    }
  }
}

// ---------------------------------------------------------------------------
extern "C" void kernel_launch(void* const* d_in, const int* in_sizes, int n_in,
                              void* d_out, int out_size, void* d_ws,
                              size_t ws_size, hipStream_t stream) {
  const float* x    = (const float*)d_in[0];
  const float* w_ih = (const float*)d_in[1];
  const float* w_hh = (const float*)d_in[2];
  const float* b_ih = (const float*)d_in[3];
  const float* b_hh = (const float*)d_in[4];
  const float* h0   = (const float*)d_in[5];
  const float* c0   = (const float*)d_in[6];
  float* out = (float*)d_out;

  // workspace layout (bytes); total ~156.3 MB. htag reuses the wihq region
  // (dead after the gemm; qh0 launches after gemm).
  char* ws = (char*)d_ws;
  unsigned* sflag = (unsigned*)ws;                    // [8][32] u32 = 1 KB
  _Float16* whhq  = (_Float16*)(ws + 264192);         // 8 MB
  _Float16* wihq  = (_Float16*)(ws + 8652800);        // 4 MB
  uint32_t* htag  = (uint32_t*)(ws + 8652800);        // 512 KB (after gemm)
  float*    bihq  = (float*)(ws + 12847104);          // 16 KB
  float*    bhhq  = (float*)(ws + 12863488);          // 16 KB
  _Float16* xq    = (_Float16*)(ws + 12879872);       // 16 MB
  _Float16* gxb   = (_Float16*)(ws + 29657088);       // 128 MB packed

  hipMemsetAsync(sflag, 0, 2048, stream);
  qf16_kernel<<<dim3(4096), 256, 0, stream>>>(w_hh, whhq, 4194304 / 4);
  qf16_kernel<<<dim3(2048), 256, 0, stream>>>(w_ih, wihq, 2097152 / 4);
  qx_kernel<<<dim3(8192), 256, 0, stream>>>(x, xq);
  qf32_kernel<<<dim3(4), 256, 0, stream>>>(b_ih, bihq, 4096 / 4);
  qf32_kernel<<<dim3(4), 256, 0, stream>>>(b_hh, bhhq, 4096 / 4);
  gemm_gx_kernel<<<dim3(128, 32), 256, 0, stream>>>(xq, wihq, bihq, gxb);
  qh0_kernel<<<dim3(64), 256, 0, stream>>>(h0, htag);  // after gemm: wihq dead
  lstm_kernel<<<dim3(256), 256, 0, stream>>>(whhq, bhhq, gxb, c0, htag, out,
                                             sflag);
}

// Round 9
// 1806.661 us; speedup vs baseline: 1.0022x; 1.0022x over previous
//
#include <hip/hip_runtime.h>
#include <stdint.h>

// ---------------------------------------------------------------------------
// FixedPointLSTM (B=64, T=256, I=512, H=1024), fixed-point Q8.8 with hard
// activations. All fxp grid values are exactly representable in fp16; fp16
// MFMA with fp32 accumulate matches the numpy reference to ~1 grid step.
//
// R9: R6's proven flag->stage protocol with the producer->consumer critical
// path shortened. (R8's tag-in-band handoff regressed: 32x 4B atomic loads
// per thread vs 8x 8B, no latency hiding at 1 wave/SIMD.)
//  - per-WAVE flags: h-stores -> wave-local vmcnt(0) -> flag store; no block
//    barrier / no out-store drain before the flag (out stores after flag).
//  - every wave polls all 128 group flags (64 lanes x u64) -> stages
//    immediately; LDS-reuse barrier sits after the poll where it's free.
//  - LDS [kt=32][264] tiling (validated in R8): ds_write_b64 staging <=2-way
//    banks, fragment reads = m97's proven GEMM pattern.
// ---------------------------------------------------------------------------

typedef _Float16 h8 __attribute__((ext_vector_type(8)));
typedef _Float16 h4 __attribute__((ext_vector_type(4)));
typedef float f4 __attribute__((ext_vector_type(4)));
typedef unsigned long long u64;

#define MFMA16(a, b, c) __builtin_amdgcn_mfma_f32_16x16x32_f16(a, b, c, 0, 0, 0)

__device__ __forceinline__ float fxp(float x) {
  float q = rintf(x * 256.0f) * 0.00390625f;
  return fminf(fmaxf(q, -128.0f), 127.99609375f);
}

// round-only: for values provably in [-128, 127.996] the clamp is a no-op.
__device__ __forceinline__ float fxp_rnd(float x) {
  return rintf(x * 256.0f) * 0.00390625f;
}

__device__ __forceinline__ float hsig(float x) {
  return fminf(fmaxf(x / 6.0f + 0.5f, 0.0f), 1.0f);  // IEEE div to match np
}

// ---- quantize fp32 -> fxp grid, store fp16 ---------------------------------
__global__ void qf16_kernel(const float* __restrict__ in,
                            _Float16* __restrict__ out, int n4) {
  int i = blockIdx.x * 256 + threadIdx.x;
  if (i < n4) {
    float4 v = ((const float4*)in)[i];
    h4 o;
    o[0] = (_Float16)fxp(v.x); o[1] = (_Float16)fxp(v.y);
    o[2] = (_Float16)fxp(v.z); o[3] = (_Float16)fxp(v.w);
    ((h4*)out)[i] = o;
  }
}

// quantize + transpose x: in [64][256][512] -> rows m = t*64+b, [16384][512]
__global__ void qx_kernel(const float* __restrict__ in,
                          _Float16* __restrict__ out) {
  int i4 = blockIdx.x * 256 + threadIdx.x;  // over 16384*128 float4s
  int col4 = i4 & 127;
  int row = i4 >> 7;  // b*256 + t
  int b = row >> 8, tt = row & 255;
  float4 v = ((const float4*)in)[i4];
  h4 o;
  o[0] = (_Float16)fxp(v.x); o[1] = (_Float16)fxp(v.y);
  o[2] = (_Float16)fxp(v.z); o[3] = (_Float16)fxp(v.w);
  ((h4*)out)[(size_t)((tt << 6) + b) * 128 + col4] = o;
}

__global__ void qf32_kernel(const float* __restrict__ in,
                            float* __restrict__ out, int n4) {
  int i = blockIdx.x * 256 + threadIdx.x;
  if (i < n4) {
    float4 v = ((const float4*)in)[i];
    float4 o;
    o.x = fxp(v.x); o.y = fxp(v.y); o.z = fxp(v.z); o.w = fxp(v.w);
    ((float4*)out)[i] = o;
  }
}

// h0 -> hbuf buffer 0, layout [grp=8][buf=2][row=8][1024] fp16
__global__ void qh0_kernel(const float* __restrict__ in,
                           _Float16* __restrict__ hbuf) {
  int i = blockIdx.x * 256 + threadIdx.x;  // over 64*1024/4
  int col4 = i & 255, b = i >> 8;
  float4 v = ((const float4*)in)[i];
  h4 o;
  o[0] = (_Float16)fxp(v.x); o[1] = (_Float16)fxp(v.y);
  o[2] = (_Float16)fxp(v.z); o[3] = (_Float16)fxp(v.w);
  *(h4*)(hbuf + (size_t)(b >> 3) * 16384 + (b & 7) * 1024 + col4 * 4) = o;
}

// ---- async global->LDS helper (width 16B; LDS dest = wave-uniform base) ----
__device__ __forceinline__ void gload_lds16(const _Float16* g, _Float16* l) {
  __builtin_amdgcn_global_load_lds(
      (const __attribute__((address_space(1))) uint32_t*)g,
      (__attribute__((address_space(3))) uint32_t*)l, 16, 0, 0);
}

// ---------------------------------------------------------------------------
// gx = fxp(x_q @ w_ih_q^T + b_ih_q), packed [T=256][oct=8][rank=32][slot=128][8]
// fp16 (128 MB). slot = (w<<5)|(qh<<4)|(gate&1)<<3|(j&7); per-entry 8 fp16 =
// [tile0 r=0..3 | tile1 r=0..3], tile = gate>>1, r = b&3, qh = (b>>2)&1.
// ---------------------------------------------------------------------------
__global__ __launch_bounds__(256) void gemm_gx_kernel(
    const _Float16* __restrict__ Xq,   // [16384][512], m = t*64+b
    const _Float16* __restrict__ Wih,  // [4096][512]
    const float* __restrict__ bih,     // [4096]
    _Float16* __restrict__ gx)         // packed, see above
{
  __shared__ _Float16 As[128 * 32];
  __shared__ _Float16 Bs[128 * 32];
  const int tid = threadIdx.x;
  const int lane = tid & 63;
  const int w = tid >> 6;
  const int wm = (w >> 1) * 64;
  const int wn = (w & 1) * 64;
  const int m0 = blockIdx.x * 128;
  const int n0 = blockIdx.y * 128;
  const int cl = lane & 15, q = lane >> 4;

  f4 acc[4][4] = {};

  for (int k0 = 0; k0 < 512; k0 += 32) {
#pragma unroll
    for (int i = 0; i < 2; i++) {
      int idx = i * 256 + tid;
      int row = idx >> 2;
      int kc = (idx & 3) << 3;
      int wbase = (i * 256 + (tid & 192)) << 3;  // wave-uniform LDS base
      gload_lds16(Xq + (size_t)(m0 + row) * 512 + k0 + kc, As + wbase);
      gload_lds16(Wih + (size_t)(n0 + row) * 512 + k0 + kc, Bs + wbase);
    }
    __syncthreads();
    h8 af[4], bf[4];
#pragma unroll
    for (int mt = 0; mt < 4; mt++)
      af[mt] = *(const h8*)(As + (wm + mt * 16 + cl) * 32 + q * 8);
#pragma unroll
    for (int nt = 0; nt < 4; nt++)
      bf[nt] = *(const h8*)(Bs + (wn + nt * 16 + cl) * 32 + q * 8);
#pragma unroll
    for (int mt = 0; mt < 4; mt++)
#pragma unroll
      for (int nt = 0; nt < 4; nt++)
        acc[mt][nt] = MFMA16(af[mt], bf[nt], acc[mt][nt]);
    __syncthreads();
  }

  const int g = n0 >> 10;  // whole n-block lies in one gate
  const int tile = g >> 1, g1 = g & 1;
#pragma unroll
  for (int nt = 0; nt < 4; nt++) {
    const int n = n0 + wn + nt * 16 + cl;
    const float bv = bih[n];
    const int j = n & 1023;
    const int rank = j >> 5, wq = (j >> 3) & 3, c7 = j & 7;
#pragma unroll
    for (int mt = 0; mt < 4; mt++) {
      const int m = m0 + wm + mt * 16 + q * 4;  // 4-aligned
      const int b = m & 63, tt = m >> 6;
      const int oct = b >> 3, qh = (b >> 2) & 1;
      const int slot = (wq << 5) | (qh << 4) | (g1 << 3) | c7;
      h4 pk;
#pragma unroll
      for (int r = 0; r < 4; r++) pk[r] = (_Float16)fxp(acc[mt][nt][r] + bv);
      *(h4*)(gx + ((((size_t)tt * 8 + oct) * 32 + rank) * 128 + slot) * 8 +
             tile * 4) = pk;
    }
  }
}

// ---------------------------------------------------------------------------
// Persistent recurrence. 256 blocks x 256 threads, a255 pin -> 1 block/CU ->
// all blocks co-resident. Block = (grp = blockIdx&7, rank = blockIdx>>3);
// group owns batch rows 8g..8g+7; rank owns h-cols rank*32..+31 x 4 gates
// (128 W_hh rows in regs). Per step:
//   gx prefetch -> all-wave poll of 128 per-wave flags (need >= t) ->
//   barrier A (LDS reuse, free here) -> stage 8x8B agent loads -> ds_write_b64
//   into [kt][264] tiles -> barrier B -> MFMA -> gates ->
//   h stores (2B agent atomics) -> wave vmcnt(0) -> per-wave flag (t+1) ->
//   out stores (after flag, off the sync path).
// Flag v from a wave  ==>  that wave passed step v-1's barrier B  ==>  its
// block finished staging h_{v-1}  ==>  buffer (v-2)&1 is consumable-free, so
// a peer at step v may overwrite it. Poll(need=t) before staging h_t.
// ---------------------------------------------------------------------------
__global__ __launch_bounds__(256, 1) void lstm_kernel(
    const _Float16* __restrict__ Whh,  // [4096][1024] quantized
    const float* __restrict__ bhh,     // [4096] quantized
    const _Float16* __restrict__ gx,   // packed [256][8][32][128][8]
    const float* __restrict__ c0,      // [64][1024]
    _Float16* __restrict__ hbuf,       // [8][2][8][1024] fp16
    float* __restrict__ out,           // [64][256][1024] ++ h_n ++ c_n
    unsigned* __restrict__ sflag)      // [8][32][4] per-wave step flags
{
  // Residency pin: force total regs/wave > 256 -> 1 wave/SIMD -> 1 block/CU.
  asm volatile("v_accvgpr_write_b32 a255, 0" ::: "a255");

  const int tid = threadIdx.x;
  const int lane = tid & 63;
  const int w = tid >> 6;
  const int cl = lane & 15, q = lane >> 4;
  const int g01 = (lane >> 3) & 1;
  const int c7 = lane & 7;

  const int grp = blockIdx.x & 7;    // batch octet
  const int rank = blockIdx.x >> 3;  // 32-column slice owner

  const int jbase = (rank << 5) + (w << 3);         // block/wave col base
  const int row0 = (g01 << 10) + jbase + c7;        // gates i/f
  const int row1 = ((g01 + 2) << 10) + jbase + c7;  // gates g/o

  // persistent B fragments: 2 tiles x 32 k-steps x 4 regs = 256 regs
  h8 B0[32], B1[32];
#pragma unroll
  for (int kt = 0; kt < 32; kt++) {
    B0[kt] = *(const h8*)(Whh + (size_t)row0 * 1024 + (kt << 5) + (q << 3));
    B1[kt] = *(const h8*)(Whh + (size_t)row1 * 1024 + (kt << 5) + (q << 3));
  }
  const float bh0 = bhh[row0], bh1 = bhh[row1];
  const int jc = jbase + c7;        // h column 0..1023
  const int lrow = ((q & 1) << 2);  // local batch row base (valid q<2)
  const bool writer = ((lane & 8) == 0) && (q < 2);

  float c_st[4], h_last[4];
#pragma unroll
  for (int r = 0; r < 4; r++) {
    c_st[r] = c0[((grp << 3) + lrow + r) * 1024 + jc];
    h_last[r] = 0.0f;
  }

  // LDS: 32 k-tiles x (8 rows x 32 halves + 8 pad) = 264 halves/tile.
  // Stage granule = u64 (4 cols of one row): thread t, load j covers
  // cols 4*((t&31)+32j).. -> tile kt = ((t&31)>>3)+4j, colInTile 4*((t&31)&7),
  // row t>>5. Write idx = kt*264 + row*32 + colInTile (u64-aligned).
  // Fragment read: kt*264 + (cl&7)*32 + q*8 -> m97's proven pattern.
  __shared__ alignas(16) _Float16 hs[32 * 264];
  const int sbase = ((tid & 31) >> 3) * 264 + (tid >> 5) * 32 +
                    ((tid & 7) << 2);          // + j*1056 halves
  const int lbase = ((tid >> 5) << 8) + (tid & 31);  // u64 idx in buf + 32j
  const int arow = cl & 7;

  const u64* hb64 = (const u64*)hbuf;  // [grp: 4096][buf: 2048] u64s
  unsigned* myflag = sflag + (((grp << 5) + rank) << 2) + w;
  const u64* f2 = (const u64*)(sflag + (grp << 7));  // 64 u64 = 128 flags

  for (int t = 0; t < 256; t++) {
    // prefetch gx_t: one coalesced 16B load per lane (overlaps the poll)
    const h8 gv8 = *(const h8*)(
        gx +
        ((((size_t)t * 8 + grp) * 32 + rank) * 128 + ((w << 5) | (lane & 31))) *
            8);

    // ---- all-wave poll: peers (and siblings) completed step t-1 ----
    {
      const unsigned need = (unsigned)t;
      int it = 0;
      for (;;) {
        u64 v = __hip_atomic_load(f2 + lane, __ATOMIC_RELAXED,
                                  __HIP_MEMORY_SCOPE_AGENT);
        bool ok = ((unsigned)v >= need) && ((unsigned)(v >> 32) >= need);
        if (__ballot(ok) == ~0ull) break;
        if (++it > (1 << 14)) break;  // hang insurance (loudly wrong)
        __builtin_amdgcn_s_sleep(1);
      }
    }
    __syncthreads();  // barrier A: all waves past MFMA of t-1 -> hs reusable

    // ---- stage h_t: 8 coalesced 8B agent loads -> ds_write_b64 ----
    {
      const u64* src = hb64 + (size_t)grp * 4096 + (size_t)(t & 1) * 2048;
      u64 v0 = __hip_atomic_load(src + lbase + 0 * 32, __ATOMIC_RELAXED, __HIP_MEMORY_SCOPE_AGENT);
      u64 v1 = __hip_atomic_load(src + lbase + 1 * 32, __ATOMIC_RELAXED, __HIP_MEMORY_SCOPE_AGENT);
      u64 v2 = __hip_atomic_load(src + lbase + 2 * 32, __ATOMIC_RELAXED, __HIP_MEMORY_SCOPE_AGENT);
      u64 v3 = __hip_atomic_load(src + lbase + 3 * 32, __ATOMIC_RELAXED, __HIP_MEMORY_SCOPE_AGENT);
      u64 v4 = __hip_atomic_load(src + lbase + 4 * 32, __ATOMIC_RELAXED, __HIP_MEMORY_SCOPE_AGENT);
      u64 v5 = __hip_atomic_load(src + lbase + 5 * 32, __ATOMIC_RELAXED, __HIP_MEMORY_SCOPE_AGENT);
      u64 v6 = __hip_atomic_load(src + lbase + 6 * 32, __ATOMIC_RELAXED, __HIP_MEMORY_SCOPE_AGENT);
      u64 v7 = __hip_atomic_load(src + lbase + 7 * 32, __ATOMIC_RELAXED, __HIP_MEMORY_SCOPE_AGENT);
      *(u64*)(hs + sbase + 0 * 1056) = v0;
      *(u64*)(hs + sbase + 1 * 1056) = v1;
      *(u64*)(hs + sbase + 2 * 1056) = v2;
      *(u64*)(hs + sbase + 3 * 1056) = v3;
      *(u64*)(hs + sbase + 4 * 1056) = v4;
      *(u64*)(hs + sbase + 5 * 1056) = v5;
      *(u64*)(hs + sbase + 6 * 1056) = v6;
      *(u64*)(hs + sbase + 7 * 1056) = v7;
    }
    __syncthreads();  // barrier B: hs fully staged

    f4 a0 = {}, a1 = {}, a2 = {}, a3 = {};
#pragma unroll
    for (int kt = 0; kt < 32; kt++) {
      h8 av = *(const h8*)(hs + kt * 264 + arow * 32 + (q << 3));
      if (kt & 1) { a1 = MFMA16(av, B0[kt], a1); a3 = MFMA16(av, B1[kt], a3); }
      else        { a0 = MFMA16(av, B0[kt], a0); a2 = MFMA16(av, B1[kt], a2); }
    }
    f4 g0 = a0 + a1;
    f4 g1 = a2 + a3;

#pragma unroll
    for (int r = 0; r < 4; r++) {
      float gv0 = fxp((float)gv8[r] + fxp(g0[r] + bh0));      // i or f
      float gv1 = fxp((float)gv8[4 + r] + fxp(g1[r] + bh1));  // g or o
      float s0 = fxp_rnd(hsig(gv0));                        // in [0,1]
      float s1t = fxp_rnd(fminf(fmaxf(gv1, -1.0f), 1.0f));  // in [-1,1]
      float s1s = fxp_rnd(hsig(gv1));
      float s1 = (lane & 8) ? s1s : s1t;
      float p0 = __shfl_xor(s0, 8);
      float p1 = __shfl_xor(s1, 8);
      float iv = writer ? s0 : p0;
      float fv = writer ? p0 : s0;
      float gv = writer ? s1 : p1;
      float ov = writer ? p1 : s1;
      float cn = fxp(fv * c_st[r] + iv * gv);
      c_st[r] = cn;
      h_last[r] = fxp_rnd(ov * fminf(fmaxf(cn, -1.0f), 1.0f));  // in [-1,1]
    }

    // ---- h stores -> wave-local drain -> per-wave flag -> out stores ----
    _Float16* hbw = hbuf + (size_t)grp * 16384 + ((t + 1) & 1) * 8192;
    if (writer) {
#pragma unroll
      for (int r = 0; r < 4; r++) {
        unsigned short hbits =
            __builtin_bit_cast(unsigned short, (_Float16)h_last[r]);
        __hip_atomic_store((unsigned short*)&hbw[(lrow + r) * 1024 + jc], hbits,
                           __ATOMIC_RELAXED, __HIP_MEMORY_SCOPE_AGENT);
      }
    }
    asm volatile("s_waitcnt vmcnt(0)" ::: "memory");  // own h stores acked
    if (lane == 0)
      __hip_atomic_store(myflag, (unsigned)(t + 1), __ATOMIC_RELAXED,
                         __HIP_MEMORY_SCOPE_AGENT);
    if (writer) {
#pragma unroll
      for (int r = 0; r < 4; r++)
        __builtin_nontemporal_store(
            h_last[r],
            &out[((size_t)((grp << 3) + lrow + r) * 256 + t) * 1024 + jc]);
    }
  }

  if (writer) {
#pragma unroll
    for (int r = 0; r < 4; r++) {
      out[16777216 + (size_t)((grp << 3) + lrow + r) * 1024 + jc] = h_last[r];
      out[16777216 + 65536 + (size_t)((grp << 3) + lrow + r) * 1024 + jc] =
          c_st[r];
    }
  }
}

// ---------------------------------------------------------------------------
extern "C" void kernel_launch(void* const* d_in, const int* in_sizes, int n_in,
                              void* d_out, int out_size, void* d_ws,
                              size_t ws_size, hipStream_t stream) {
  const float* x    = (const float*)d_in[0];
  const float* w_ih = (const float*)d_in[1];
  const float* w_hh = (const float*)d_in[2];
  const float* b_ih = (const float*)d_in[3];
  const float* b_hh = (const float*)d_in[4];
  const float* h0   = (const float*)d_in[5];
  const float* c0   = (const float*)d_in[6];
  float* out = (float*)d_out;

  // workspace layout (bytes); total ~156.3 MB
  char* ws = (char*)d_ws;
  unsigned* sflag = (unsigned*)ws;                    // [8][32][4] u32 = 4 KB
  _Float16* hbuf  = (_Float16*)(ws + 4096);           // 8*2*8*1024*2 = 256 KB
  _Float16* whhq  = (_Float16*)(ws + 266240);         // 8 MB
  _Float16* wihq  = (_Float16*)(ws + 8654848);        // 4 MB
  float*    bihq  = (float*)(ws + 12849152);          // 16 KB
  float*    bhhq  = (float*)(ws + 12865536);          // 16 KB
  _Float16* xq    = (_Float16*)(ws + 12881920);       // 16 MB
  _Float16* gxb   = (_Float16*)(ws + 29659136);       // 128 MB packed

  hipMemsetAsync(sflag, 0, 4096, stream);
  qf16_kernel<<<dim3(4096), 256, 0, stream>>>(w_hh, whhq, 4194304 / 4);
  qf16_kernel<<<dim3(2048), 256, 0, stream>>>(w_ih, wihq, 2097152 / 4);
  qx_kernel<<<dim3(8192), 256, 0, stream>>>(x, xq);
  qh0_kernel<<<dim3(64), 256, 0, stream>>>(h0, hbuf);
  qf32_kernel<<<dim3(4), 256, 0, stream>>>(b_ih, bihq, 4096 / 4);
  qf32_kernel<<<dim3(4), 256, 0, stream>>>(b_hh, bhhq, 4096 / 4);
  gemm_gx_kernel<<<dim3(128, 32), 256, 0, stream>>>(xq, wihq, bihq, gxb);
  lstm_kernel<<<dim3(256), 256, 0, stream>>>(whhq, bhhq, gxb, c0, hbuf, out,
                                             sflag);
}

// Round 10
// 1068.462 us; speedup vs baseline: 1.6946x; 1.6909x over previous
//
#include <hip/hip_runtime.h>
#include <stdint.h>

// ---------------------------------------------------------------------------
// FixedPointLSTM (B=64, T=256, I=512, H=1024), fixed-point Q8.8 with hard
// activations. All fxp grid values are exactly representable in fp16; fp16
// MFMA with fp32 accumulate matches the numpy reference to ~1 grid step.
//
// R10 = R6 (best: 1086 us lstm) + three surgical fixes, protocol untouched:
//  1) coalesced stage loads (R6 was 64B-strided per instruction),
//  2) LDS staging writes at 4-way banks (R6: 16-way, 5.9e7 conflict cyc),
//     fragment reads keep R6's verified conflict-free arow*1032 pattern,
//  3) out-stores moved AFTER the flag (pre-flag barrier drains only the 2B
//     h atomics, not the HBM-bound nontemporal out stores).
// R8 (tag-in-band) and R9 (per-wave flags + all-wave poll) both regressed:
// the per-block-flag / w0-poll / barrier-then-flag structure stays.
// ---------------------------------------------------------------------------

typedef _Float16 h8 __attribute__((ext_vector_type(8)));
typedef _Float16 h4 __attribute__((ext_vector_type(4)));
typedef float f4 __attribute__((ext_vector_type(4)));
typedef unsigned long long u64;

#define MFMA16(a, b, c) __builtin_amdgcn_mfma_f32_16x16x32_f16(a, b, c, 0, 0, 0)

__device__ __forceinline__ float fxp(float x) {
  float q = rintf(x * 256.0f) * 0.00390625f;
  return fminf(fmaxf(q, -128.0f), 127.99609375f);
}

// round-only: for values provably in [-128, 127.996] the clamp is a no-op.
__device__ __forceinline__ float fxp_rnd(float x) {
  return rintf(x * 256.0f) * 0.00390625f;
}

__device__ __forceinline__ float hsig(float x) {
  return fminf(fmaxf(x / 6.0f + 0.5f, 0.0f), 1.0f);  // IEEE div to match np
}

// ---- quantize fp32 -> fxp grid, store fp16 ---------------------------------
__global__ void qf16_kernel(const float* __restrict__ in,
                            _Float16* __restrict__ out, int n4) {
  int i = blockIdx.x * 256 + threadIdx.x;
  if (i < n4) {
    float4 v = ((const float4*)in)[i];
    h4 o;
    o[0] = (_Float16)fxp(v.x); o[1] = (_Float16)fxp(v.y);
    o[2] = (_Float16)fxp(v.z); o[3] = (_Float16)fxp(v.w);
    ((h4*)out)[i] = o;
  }
}

// quantize + transpose x: in [64][256][512] -> rows m = t*64+b, [16384][512]
__global__ void qx_kernel(const float* __restrict__ in,
                          _Float16* __restrict__ out) {
  int i4 = blockIdx.x * 256 + threadIdx.x;  // over 16384*128 float4s
  int col4 = i4 & 127;
  int row = i4 >> 7;  // b*256 + t
  int b = row >> 8, tt = row & 255;
  float4 v = ((const float4*)in)[i4];
  h4 o;
  o[0] = (_Float16)fxp(v.x); o[1] = (_Float16)fxp(v.y);
  o[2] = (_Float16)fxp(v.z); o[3] = (_Float16)fxp(v.w);
  ((h4*)out)[(size_t)((tt << 6) + b) * 128 + col4] = o;
}

__global__ void qf32_kernel(const float* __restrict__ in,
                            float* __restrict__ out, int n4) {
  int i = blockIdx.x * 256 + threadIdx.x;
  if (i < n4) {
    float4 v = ((const float4*)in)[i];
    float4 o;
    o.x = fxp(v.x); o.y = fxp(v.y); o.z = fxp(v.z); o.w = fxp(v.w);
    ((float4*)out)[i] = o;
  }
}

// h0 -> hbuf buffer 0, layout [grp=8][buf=2][row=8][1024] fp16
__global__ void qh0_kernel(const float* __restrict__ in,
                           _Float16* __restrict__ hbuf) {
  int i = blockIdx.x * 256 + threadIdx.x;  // over 64*1024/4
  int col4 = i & 255, b = i >> 8;
  float4 v = ((const float4*)in)[i];
  h4 o;
  o[0] = (_Float16)fxp(v.x); o[1] = (_Float16)fxp(v.y);
  o[2] = (_Float16)fxp(v.z); o[3] = (_Float16)fxp(v.w);
  *(h4*)(hbuf + (size_t)(b >> 3) * 16384 + (b & 7) * 1024 + col4 * 4) = o;
}

// ---- async global->LDS helper (width 16B; LDS dest = wave-uniform base) ----
__device__ __forceinline__ void gload_lds16(const _Float16* g, _Float16* l) {
  __builtin_amdgcn_global_load_lds(
      (const __attribute__((address_space(1))) uint32_t*)g,
      (__attribute__((address_space(3))) uint32_t*)l, 16, 0, 0);
}

// ---------------------------------------------------------------------------
// gx = fxp(x_q @ w_ih_q^T + b_ih_q), packed [T=256][oct=8][rank=32][slot=128][8]
// fp16 (128 MB). slot = (w<<5)|(qh<<4)|(gate&1)<<3|(j&7); per-entry 8 fp16 =
// [tile0 r=0..3 | tile1 r=0..3], tile = gate>>1, r = b&3, qh = (b>>2)&1.
// ---------------------------------------------------------------------------
__global__ __launch_bounds__(256) void gemm_gx_kernel(
    const _Float16* __restrict__ Xq,   // [16384][512], m = t*64+b
    const _Float16* __restrict__ Wih,  // [4096][512]
    const float* __restrict__ bih,     // [4096]
    _Float16* __restrict__ gx)         // packed, see above
{
  __shared__ _Float16 As[128 * 32];
  __shared__ _Float16 Bs[128 * 32];
  const int tid = threadIdx.x;
  const int lane = tid & 63;
  const int w = tid >> 6;
  const int wm = (w >> 1) * 64;
  const int wn = (w & 1) * 64;
  const int m0 = blockIdx.x * 128;
  const int n0 = blockIdx.y * 128;
  const int cl = lane & 15, q = lane >> 4;

  f4 acc[4][4] = {};

  for (int k0 = 0; k0 < 512; k0 += 32) {
#pragma unroll
    for (int i = 0; i < 2; i++) {
      int idx = i * 256 + tid;
      int row = idx >> 2;
      int kc = (idx & 3) << 3;
      int wbase = (i * 256 + (tid & 192)) << 3;  // wave-uniform LDS base
      gload_lds16(Xq + (size_t)(m0 + row) * 512 + k0 + kc, As + wbase);
      gload_lds16(Wih + (size_t)(n0 + row) * 512 + k0 + kc, Bs + wbase);
    }
    __syncthreads();
    h8 af[4], bf[4];
#pragma unroll
    for (int mt = 0; mt < 4; mt++)
      af[mt] = *(const h8*)(As + (wm + mt * 16 + cl) * 32 + q * 8);
#pragma unroll
    for (int nt = 0; nt < 4; nt++)
      bf[nt] = *(const h8*)(Bs + (wn + nt * 16 + cl) * 32 + q * 8);
#pragma unroll
    for (int mt = 0; mt < 4; mt++)
#pragma unroll
      for (int nt = 0; nt < 4; nt++)
        acc[mt][nt] = MFMA16(af[mt], bf[nt], acc[mt][nt]);
    __syncthreads();
  }

  const int g = n0 >> 10;  // whole n-block lies in one gate
  const int tile = g >> 1, g1 = g & 1;
#pragma unroll
  for (int nt = 0; nt < 4; nt++) {
    const int n = n0 + wn + nt * 16 + cl;
    const float bv = bih[n];
    const int j = n & 1023;
    const int rank = j >> 5, wq = (j >> 3) & 3, c7 = j & 7;
#pragma unroll
    for (int mt = 0; mt < 4; mt++) {
      const int m = m0 + wm + mt * 16 + q * 4;  // 4-aligned
      const int b = m & 63, tt = m >> 6;
      const int oct = b >> 3, qh = (b >> 2) & 1;
      const int slot = (wq << 5) | (qh << 4) | (g1 << 3) | c7;
      h4 pk;
#pragma unroll
      for (int r = 0; r < 4; r++) pk[r] = (_Float16)fxp(acc[mt][nt][r] + bv);
      *(h4*)(gx + ((((size_t)tt * 8 + oct) * 32 + rank) * 128 + slot) * 8 +
             tile * 4) = pk;
    }
  }
}

// ---------------------------------------------------------------------------
// Persistent recurrence. 256 blocks x 256 threads, a255 pin -> 1 block/CU ->
// all blocks co-resident. Block = (grp = blockIdx&7, rank = blockIdx>>3);
// group owns batch rows 8g..8g+7; rank owns h-cols rank*32..+31 x 4 gates
// (128 W_hh rows in regs). Per step (R6 protocol):
//   gx prefetch -> w0 polls 32 per-block flags -> barrier ->
//   stage 8x8B coalesced agent loads -> ds_write_b64 (4-way banks) ->
//   barrier -> MFMA -> gates -> h stores (2B agent atomics) ->
//   barrier (drains h only) -> tid0 flag -> out stores (off sync path).
// ---------------------------------------------------------------------------
__global__ __launch_bounds__(256, 1) void lstm_kernel(
    const _Float16* __restrict__ Whh,  // [4096][1024] quantized
    const float* __restrict__ bhh,     // [4096] quantized
    const _Float16* __restrict__ gx,   // packed [256][8][32][128][8]
    const float* __restrict__ c0,      // [64][1024]
    _Float16* __restrict__ hbuf,       // [8][2][8][1024] fp16
    float* __restrict__ out,           // [64][256][1024] ++ h_n ++ c_n
    unsigned* __restrict__ flags)      // [8][32]
{
  // Residency pin: force total regs/wave > 256 -> 1 wave/SIMD -> 1 block/CU.
  asm volatile("v_accvgpr_write_b32 a255, 0" ::: "a255");

  const int tid = threadIdx.x;
  const int lane = tid & 63;
  const int w = tid >> 6;
  const int cl = lane & 15, q = lane >> 4;
  const int g01 = (lane >> 3) & 1;
  const int c7 = lane & 7;

  const int grp = blockIdx.x & 7;    // batch octet
  const int rank = blockIdx.x >> 3;  // 32-column slice owner

  const int jbase = (rank << 5) + (w << 3);         // block/wave col base
  const int row0 = (g01 << 10) + jbase + c7;        // gates i/f
  const int row1 = ((g01 + 2) << 10) + jbase + c7;  // gates g/o

  // persistent B fragments: 2 tiles x 32 k-steps x 4 regs = 256 regs
  h8 B0[32], B1[32];
#pragma unroll
  for (int kt = 0; kt < 32; kt++) {
    B0[kt] = *(const h8*)(Whh + (size_t)row0 * 1024 + (kt << 5) + (q << 3));
    B1[kt] = *(const h8*)(Whh + (size_t)row1 * 1024 + (kt << 5) + (q << 3));
  }
  const float bh0 = bhh[row0], bh1 = bhh[row1];
  const int jc = jbase + c7;        // h column 0..1023
  const int lrow = ((q & 1) << 2);  // local batch row base (valid q<2)
  const bool writer = ((lane & 8) == 0) && (q < 2);

  float c_st[4], h_last[4];
#pragma unroll
  for (int r = 0; r < 4; r++) {
    c_st[r] = c0[((grp << 3) + lrow + r) * 1024 + jc];
    h_last[r] = 0.0f;
  }

  // LDS h stage: 8 rows x 1032 halves (pad +8: fragment reads arow*1032 are
  // conflict-free, verified in R6). Staging (new): thread (row=tid>>5,
  // c=tid&31) loads u64s c+32j of its row (coalesced 256B/32 lanes), writes
  // LDS at row*1032 + 4c + 128j halves -> 4-way banks (was 16-way).
  __shared__ alignas(16) _Float16 hs[8 * 1032];
  const int arow = cl & 7;
  const u64* hb64 = (const u64*)hbuf;  // [grp: 4096][buf: 2048] u64s
  const size_t lsrc = (size_t)grp * 4096 + (size_t)((tid >> 5) << 8) + (tid & 31);
  _Float16* ldst = hs + (tid >> 5) * 1032 + ((tid & 31) << 2);

  unsigned* myflag = flags + (grp << 5) + rank;
  const u64* f2 = (const u64*)(flags + (grp << 5));  // 16 u64 per group

  for (int t = 0; t < 256; t++) {
    // prefetch gx_t: one coalesced 16B load per lane (overlaps the poll)
    const h8 gv8 = *(const h8*)(
        gx +
        ((((size_t)t * 8 + grp) * 32 + rank) * 128 + ((w << 5) | (lane & 31))) *
            8);

    if (t) {
      if (w == 0) {
        const unsigned tt = (unsigned)t;
        int it = 0;
        for (;;) {
          u64 v = __hip_atomic_load(&f2[lane & 15], __ATOMIC_RELAXED,
                                    __HIP_MEMORY_SCOPE_AGENT);
          bool ok = ((unsigned)v >= tt) && ((unsigned)(v >> 32) >= tt);
          if (__ballot(ok) == ~0ull) break;
          if (++it > (1 << 14)) break;  // hang insurance (loudly wrong)
          __builtin_amdgcn_s_sleep(1);
        }
      }
      __syncthreads();
    }

    // ---- stage h_t (16KB): 8 coalesced 8B agent loads -> ds_write_b64 ----
    {
      const u64* src = hb64 + lsrc + (size_t)(t & 1) * 2048;
      u64 v0 = __hip_atomic_load(src + 0 * 32, __ATOMIC_RELAXED, __HIP_MEMORY_SCOPE_AGENT);
      u64 v1 = __hip_atomic_load(src + 1 * 32, __ATOMIC_RELAXED, __HIP_MEMORY_SCOPE_AGENT);
      u64 v2 = __hip_atomic_load(src + 2 * 32, __ATOMIC_RELAXED, __HIP_MEMORY_SCOPE_AGENT);
      u64 v3 = __hip_atomic_load(src + 3 * 32, __ATOMIC_RELAXED, __HIP_MEMORY_SCOPE_AGENT);
      u64 v4 = __hip_atomic_load(src + 4 * 32, __ATOMIC_RELAXED, __HIP_MEMORY_SCOPE_AGENT);
      u64 v5 = __hip_atomic_load(src + 5 * 32, __ATOMIC_RELAXED, __HIP_MEMORY_SCOPE_AGENT);
      u64 v6 = __hip_atomic_load(src + 6 * 32, __ATOMIC_RELAXED, __HIP_MEMORY_SCOPE_AGENT);
      u64 v7 = __hip_atomic_load(src + 7 * 32, __ATOMIC_RELAXED, __HIP_MEMORY_SCOPE_AGENT);
      *(u64*)(ldst + 0 * 128) = v0;
      *(u64*)(ldst + 1 * 128) = v1;
      *(u64*)(ldst + 2 * 128) = v2;
      *(u64*)(ldst + 3 * 128) = v3;
      *(u64*)(ldst + 4 * 128) = v4;
      *(u64*)(ldst + 5 * 128) = v5;
      *(u64*)(ldst + 6 * 128) = v6;
      *(u64*)(ldst + 7 * 128) = v7;
    }
    __syncthreads();

    f4 a0 = {}, a1 = {}, a2 = {}, a3 = {};
#pragma unroll
    for (int kt = 0; kt < 32; kt++) {
      h8 av = *(const h8*)(hs + arow * 1032 + (kt << 5) + (q << 3));
      if (kt & 1) { a1 = MFMA16(av, B0[kt], a1); a3 = MFMA16(av, B1[kt], a3); }
      else        { a0 = MFMA16(av, B0[kt], a0); a2 = MFMA16(av, B1[kt], a2); }
    }
    f4 g0 = a0 + a1;
    f4 g1 = a2 + a3;

    _Float16* hbw = hbuf + (size_t)grp * 16384 + ((t + 1) & 1) * 8192;
#pragma unroll
    for (int r = 0; r < 4; r++) {
      float gv0 = fxp((float)gv8[r] + fxp(g0[r] + bh0));      // i or f
      float gv1 = fxp((float)gv8[4 + r] + fxp(g1[r] + bh1));  // g or o
      float s0 = fxp_rnd(hsig(gv0));                        // in [0,1]
      float s1t = fxp_rnd(fminf(fmaxf(gv1, -1.0f), 1.0f));  // in [-1,1]
      float s1s = fxp_rnd(hsig(gv1));
      float s1 = (lane & 8) ? s1s : s1t;
      float p0 = __shfl_xor(s0, 8);
      float p1 = __shfl_xor(s1, 8);
      float iv = writer ? s0 : p0;
      float fv = writer ? p0 : s0;
      float gv = writer ? s1 : p1;
      float ov = writer ? p1 : s1;
      float cn = fxp(fv * c_st[r] + iv * gv);
      c_st[r] = cn;
      float hn = fxp_rnd(ov * fminf(fmaxf(cn, -1.0f), 1.0f));  // in [-1,1]
      h_last[r] = hn;
      if (writer) {
        unsigned short hbits = __builtin_bit_cast(unsigned short, (_Float16)hn);
        __hip_atomic_store((unsigned short*)&hbw[(lrow + r) * 1024 + jc], hbits,
                           __ATOMIC_RELAXED, __HIP_MEMORY_SCOPE_AGENT);
      }
    }
    __syncthreads();  // drains the h atomic stores (out stores not yet issued)
    if (tid == 0)
      __hip_atomic_store(myflag, (unsigned)(t + 1), __ATOMIC_RELAXED,
                         __HIP_MEMORY_SCOPE_AGENT);
    // out stores after the flag: drain overlaps the next step's poll/stage
    if (writer) {
#pragma unroll
      for (int r = 0; r < 4; r++)
        __builtin_nontemporal_store(
            h_last[r],
            &out[((size_t)((grp << 3) + lrow + r) * 256 + t) * 1024 + jc]);
    }
  }

  if (writer) {
#pragma unroll
    for (int r = 0; r < 4; r++) {
      out[16777216 + (size_t)((grp << 3) + lrow + r) * 1024 + jc] = h_last[r];
      out[16777216 + 65536 + (size_t)((grp << 3) + lrow + r) * 1024 + jc] =
          c_st[r];
    }
  }
}

// ---------------------------------------------------------------------------
extern "C" void kernel_launch(void* const* d_in, const int* in_sizes, int n_in,
                              void* d_out, int out_size, void* d_ws,
                              size_t ws_size, hipStream_t stream) {
  const float* x    = (const float*)d_in[0];
  const float* w_ih = (const float*)d_in[1];
  const float* w_hh = (const float*)d_in[2];
  const float* b_ih = (const float*)d_in[3];
  const float* b_hh = (const float*)d_in[4];
  const float* h0   = (const float*)d_in[5];
  const float* c0   = (const float*)d_in[6];
  float* out = (float*)d_out;

  // workspace layout (bytes); total ~156.3 MB
  char* ws = (char*)d_ws;
  unsigned* flags = (unsigned*)ws;                    // [8][32] u32 = 1 KB
  _Float16* hbuf  = (_Float16*)(ws + 2048);           // 8*2*8*1024*2 = 256 KB
  _Float16* whhq  = (_Float16*)(ws + 264192);         // 8 MB
  _Float16* wihq  = (_Float16*)(ws + 8652800);        // 4 MB
  float*    bihq  = (float*)(ws + 12847104);          // 16 KB
  float*    bhhq  = (float*)(ws + 12863488);          // 16 KB
  _Float16* xq    = (_Float16*)(ws + 12879872);       // 16 MB
  _Float16* gxb   = (_Float16*)(ws + 29657088);       // 128 MB packed

  hipMemsetAsync(flags, 0, 2048, stream);
  qf16_kernel<<<dim3(4096), 256, 0, stream>>>(w_hh, whhq, 4194304 / 4);
  qf16_kernel<<<dim3(2048), 256, 0, stream>>>(w_ih, wihq, 2097152 / 4);
  qx_kernel<<<dim3(8192), 256, 0, stream>>>(x, xq);
  qh0_kernel<<<dim3(64), 256, 0, stream>>>(h0, hbuf);
  qf32_kernel<<<dim3(4), 256, 0, stream>>>(b_ih, bihq, 4096 / 4);
  qf32_kernel<<<dim3(4), 256, 0, stream>>>(b_hh, bhhq, 4096 / 4);
  gemm_gx_kernel<<<dim3(128, 32), 256, 0, stream>>>(xq, wihq, bihq, gxb);
  lstm_kernel<<<dim3(256), 256, 0, stream>>>(whhq, bhhq, gxb, c0, hbuf, out,
                                             flags);
}